// Round 12
// baseline (232.940 us; speedup 1.0000x reference)
//
#include <hip/hip_runtime.h>
#include <hip/hip_cooperative_groups.h>
#include <math.h>

namespace cg = cooperative_groups;

#define NF 512
#define NF2 (NF * NF)
#define ROWLEN 580            // padded scratch row length (LPAD(511)=574 max)
#define PI_F 3.14159265358979323846f

#define LPAD(q) ((q) + ((q) >> 3))   // LDS pad for butterfly scatter

__device__ inline float2 cadd(float2 a, float2 b) { return make_float2(a.x + b.x, a.y + b.y); }
__device__ inline float2 csub(float2 a, float2 b) { return make_float2(a.x - b.x, a.y - b.y); }
__device__ inline float2 cmul(float2 a, float2 b) {
    return make_float2(a.x * b.x - a.y * b.y, a.x * b.y + a.y * b.x);
}

// 8-point DFT in registers, natural order in/out. dsign=-1 fwd, +1 inv.
__device__ inline void fft8(float2 x[8], float dsign) {
    const float s = 0.70710678118654752440f;
    float2 a0 = cadd(x[0], x[4]), a1 = cadd(x[1], x[5]);
    float2 a2 = cadd(x[2], x[6]), a3 = cadd(x[3], x[7]);
    float2 b0 = csub(x[0], x[4]), b1 = csub(x[1], x[5]);
    float2 b2 = csub(x[2], x[6]), b3 = csub(x[3], x[7]);
    b1 = cmul(b1, make_float2(s, dsign * s));
    b2 = make_float2(-dsign * b2.y, dsign * b2.x);
    b3 = cmul(b3, make_float2(-s, dsign * s));
    float2 c0 = cadd(a0, a2), c1 = cadd(a1, a3);
    float2 c2 = csub(a0, a2), c3 = csub(a1, a3);
    c3 = make_float2(-dsign * c3.y, dsign * c3.x);
    float2 d0 = cadd(b0, b2), d1 = cadd(b1, b3);
    float2 d2 = csub(b0, b2), d3 = csub(b1, b3);
    d3 = make_float2(-dsign * d3.y, dsign * d3.x);
    x[0] = cadd(c0, c1); x[4] = csub(c0, c1);
    x[2] = cadd(c2, c3); x[6] = csub(c2, c3);
    x[1] = cadd(d0, d1); x[5] = csub(d0, d1);
    x[3] = cadd(d2, d3); x[7] = csub(d2, d3);
}

__device__ inline void twiddle8(float2 x[8], float2 wb) {
    float2 tw = wb;
    x[1] = cmul(x[1], tw); tw = cmul(tw, wb);
    x[2] = cmul(x[2], tw); tw = cmul(tw, wb);
    x[3] = cmul(x[3], tw); tw = cmul(tw, wb);
    x[4] = cmul(x[4], tw); tw = cmul(tw, wb);
    x[5] = cmul(x[5], tw); tw = cmul(tw, wb);
    x[6] = cmul(x[6], tw); tw = cmul(tw, wb);
    x[7] = cmul(x[7], tw);
}

// Radix-8 Stockham FFT-512. In: x[j] = data[b + 64j]. Out: x[p] = Y[64p + b].
// Per-wavegroup scratch bufA/bufB; 2 internal block barriers. bufA reusable after.
__device__ inline void fft512_regs(float2 x[8], int b, float2* bufA, float2* bufB,
                                   const float2* Wt, float dsign) {
    fft8(x, dsign);
    float2 wb0 = make_float2(Wt[b].x, dsign * Wt[b].y);
    twiddle8(x, wb0);
#pragma unroll
    for (int p = 0; p < 8; ++p) bufA[9 * b + p] = x[p];   // LPAD(8b+p) = 9b+p
    __syncthreads();
#pragma unroll
    for (int j = 0; j < 8; ++j) x[j] = bufA[LPAD(b + 64 * j)];
    fft8(x, dsign);
    float2 wb1 = make_float2(Wt[b & ~7].x, dsign * Wt[b & ~7].y);   // W512[8u]
    twiddle8(x, wb1);
    int base = (b >> 3) * 64 + (b & 7);
#pragma unroll
    for (int p = 0; p < 8; ++p) bufB[LPAD(base + 8 * p)] = x[p];
    __syncthreads();
#pragma unroll
    for (int j = 0; j < 8; ++j) x[j] = bufB[LPAD(b + 64 * j)];
    fft8(x, dsign);
}

#define HT 38
#define HT2 (HT * HT)
#define CT 36
#define CT2 (CT * CT)

// ---- Single cooperative kernel: whole FlowLenia step. 256 blocks x 512 threads. ----
__global__ __launch_bounds__(512) void k_mega(const float* __restrict__ A,
                                              const float* __restrict__ K,
                                              const float* __restrict__ mm,
                                              const float* __restrict__ ss,
                                              const float* __restrict__ hh,
                                              const int* __restrict__ c0,
                                              const int* __restrict__ c1,
                                              float2* __restrict__ Z,
                                              float2* __restrict__ tmpT,
                                              float* __restrict__ G,
                                              float* __restrict__ out) {
    __shared__ float2 RS[14][NF];       // 57,344 B (phase2 spectra / phase3 transpose / phase4 alias)
    __shared__ float2 SCA[8][ROWLEN];   // 37,120 B (FFT scratch A / phase1 transpose / phase4 alias)
    __shared__ float2 SCB[8][ROWLEN];   // 37,120 B (FFT scratch B)
    __shared__ float2 Wt[512];          //  4,096 B
    cg::grid_group grid = cg::this_grid();
    int tid = threadIdx.x;
    int rr_ = tid >> 6, bb_ = tid & 63;
    int blk = blockIdx.x;
    {
        float sn, cs;
        sincosf((PI_F / 256.0f) * (float)tid, &sn, &cs);
        Wt[tid] = make_float2(cs, sn);
    }
    __syncthreads();

    // ---------- Phase 1: forward FFT along y, packed pairs of real planes. ----------
    //  p0=A0+iA1  p1=A2+iK0  p2=K1+iK2  p3=K3+iK4  p4=K5+iK6  p5=K7+iK8  p6=K9
    // 448 chunks of 8 rows; 2 batches of 256 blocks. Out transposed: Z[p][ky][x].
    for (int t = 0; t < 2; ++t) {
        int c = t * 256 + blk;
        int cc = c < 448 ? c : 447;
        int p = cc >> 6;
        int x0 = (cc & 63) << 3;
        int row = x0 + rr_;
        const float* bre; int sre, cre;
        const float* bim; int sim, cim;
        switch (p) {
            case 0: bre = A; sre = 3; cre = 0; bim = A; sim = 3; cim = 1; break;
            case 1: bre = A; sre = 3; cre = 2; bim = K; sim = 10; cim = 0; break;
            case 2: bre = K; sre = 10; cre = 1; bim = K; sim = 10; cim = 2; break;
            case 3: bre = K; sre = 10; cre = 3; bim = K; sim = 10; cim = 4; break;
            case 4: bre = K; sre = 10; cre = 5; bim = K; sim = 10; cim = 6; break;
            case 5: bre = K; sre = 10; cre = 7; bim = K; sim = 10; cim = 8; break;
            default: bre = K; sre = 10; cre = 9; bim = nullptr; sim = 0; cim = 0; break;
        }
        float2 x[8];
#pragma unroll
        for (int j = 0; j < 8; ++j) {
            int idx = (row << 9) + bb_ + 64 * j;
            float vr = bre[idx * sre + cre];
            float vi = bim ? bim[idx * sim + cim] : 0.0f;
            x[j] = make_float2(vr, vi);
        }
        fft512_regs(x, bb_, &SCA[rr_][0], &SCB[rr_][0], Wt, -1.0f);
#pragma unroll
        for (int p2 = 0; p2 < 8; ++p2) SCA[rr_][LPAD(64 * p2 + bb_)] = x[p2];
        __syncthreads();
        if (c < 448) {
            for (int i = tid; i < 8 * NF; i += 512) {
                int r2 = i & 7, ky = i >> 3;
                Z[(size_t)((p << 9) + ky) * NF + x0 + r2] = SCA[r2][LPAD(ky)];
            }
        }
        __syncthreads();
    }
    grid.sync();

    // ---------- Phase 2: row FFT + Hermitian-unpacked spectral products + inverse kx. ----------
    // Block b owns rows (b, 512-b); block 0 owns {0,256} (self-mirror).
    {
        int b = blk;
        bool selfm = (b == 0);
        int r1 = selfm ? 0 : b;
        int r2 = selfm ? 256 : NF - b;
        for (int batch = 0; batch < 2; ++batch) {
            int ridx = batch * 8 + rr_;
            int rc = ridx < 14 ? ridx : 13;
            int p = rc >> 1, sl = rc & 1;
            int row = sl ? r2 : r1;
            float2 x[8];
            size_t base = (size_t)((p << 9) + row) * NF;
#pragma unroll
            for (int jj = 0; jj < 8; ++jj) x[jj] = Z[base + bb_ + 64 * jj];
            fft512_regs(x, bb_, &SCA[rr_][0], &SCB[rr_][0], Wt, -1.0f);
            if (ridx < 14) {
#pragma unroll
                for (int pp = 0; pp < 8; ++pp) RS[ridx][64 * pp + bb_] = x[pp];
            }
        }
        __syncthreads();
        for (int batch = 0; batch < 2; ++batch) {
            int q = batch * 8 + rr_;
            int qc = q < 10 ? q : 8;
            int j = qc >> 1, sl = qc & 1;
            int k1 = 2 * j, k2 = 2 * j + 1;
            int pK1 = (k1 == 0) ? 1 : 2 + ((k1 - 1) >> 1);
            int sK1 = (k1 == 0) ? 1 : ((k1 - 1) & 1);
            int pK2 = 2 + ((k2 - 1) >> 1);
            int sK2 = (k2 - 1) & 1;
            int cA1 = c0[k1], cA2 = c0[k2];
            int pA1 = cA1 >> 1, sA1 = cA1 & 1;
            int pA2 = cA2 >> 1, sA2 = cA2 & 1;
            int mo = selfm ? sl : (1 - sl);
            float2 x[8];
#pragma unroll
            for (int jj = 0; jj < 8; ++jj) {
                int kx = bb_ + 64 * jj;
                int mkx = (NF - kx) & (NF - 1);
                float2 zr, zm, fk1, fk2, fa1, fa2;
                zr = RS[2 * pK1 + sl][kx]; zm = RS[2 * pK1 + mo][mkx];
                fk1 = sK1 == 0 ? make_float2(0.5f * (zr.x + zm.x), 0.5f * (zr.y - zm.y))
                               : make_float2(0.5f * (zr.y + zm.y), 0.5f * (zm.x - zr.x));
                zr = RS[2 * pK2 + sl][kx]; zm = RS[2 * pK2 + mo][mkx];
                fk2 = sK2 == 0 ? make_float2(0.5f * (zr.x + zm.x), 0.5f * (zr.y - zm.y))
                               : make_float2(0.5f * (zr.y + zm.y), 0.5f * (zm.x - zr.x));
                zr = RS[2 * pA1 + sl][kx]; zm = RS[2 * pA1 + mo][mkx];
                fa1 = sA1 == 0 ? make_float2(0.5f * (zr.x + zm.x), 0.5f * (zr.y - zm.y))
                               : make_float2(0.5f * (zr.y + zm.y), 0.5f * (zm.x - zr.x));
                if (cA2 == cA1) fa2 = fa1;
                else {
                    zr = RS[2 * pA2 + sl][kx]; zm = RS[2 * pA2 + mo][mkx];
                    fa2 = sA2 == 0 ? make_float2(0.5f * (zr.x + zm.x), 0.5f * (zr.y - zm.y))
                                   : make_float2(0.5f * (zr.y + zm.y), 0.5f * (zm.x - zr.x));
                }
                float t1x = fk1.x * fa1.x - fk1.y * fa1.y;
                float t1y = fk1.x * fa1.y + fk1.y * fa1.x;
                float t2x = fk2.x * fa2.x - fk2.y * fa2.y;
                float t2y = fk2.x * fa2.y + fk2.y * fa2.x;
                float sgn = ((kx + b) & 1) ? -1.0f : 1.0f;
                x[jj] = make_float2((t1x - t2y) * sgn, (t1y + t2x) * sgn);
            }
            fft512_regs(x, bb_, &SCA[rr_][0], &SCB[rr_][0], Wt, +1.0f);
            if (q < 10) {
                int orow = sl ? r2 : r1;
                size_t obase = ((size_t)j * NF + orow) * NF;
#pragma unroll
                for (int pp = 0; pp < 8; ++pp) tmpT[obase + 64 * pp + bb_] = x[pp];
            }
        }
    }
    grid.sync();

    // ---------- Phase 3: inverse FFT along ky + growth epilogue. ----------
    // 2560 columns (5 j-planes x 512 x); 8 cols/block/batch; 2 batches.
    for (int t = 0; t < 2; ++t) {
        int qb = t * 2048 + blk * 8;
        bool valid = qb < 2560;
        int qbc = valid ? qb : 2552;
        int j = qbc >> 9;
        int x0 = qbc & 511;
        {
            const float2* src = tmpT + ((size_t)j * NF + tid) * NF + x0;
            float4 v0 = *(const float4*)(src + 0);
            float4 v1 = *(const float4*)(src + 2);
            float4 v2 = *(const float4*)(src + 4);
            float4 v3 = *(const float4*)(src + 6);
            RS[0][tid] = make_float2(v0.x, v0.y); RS[1][tid] = make_float2(v0.z, v0.w);
            RS[2][tid] = make_float2(v1.x, v1.y); RS[3][tid] = make_float2(v1.z, v1.w);
            RS[4][tid] = make_float2(v2.x, v2.y); RS[5][tid] = make_float2(v2.z, v2.w);
            RS[6][tid] = make_float2(v3.x, v3.y); RS[7][tid] = make_float2(v3.z, v3.w);
        }
        __syncthreads();
        float2 x[8];
#pragma unroll
        for (int jj = 0; jj < 8; ++jj) x[jj] = RS[rr_][bb_ + 64 * jj];
        fft512_regs(x, bb_, &SCA[rr_][0], &SCB[rr_][0], Wt, +1.0f);
        if (valid) {
            int k1 = 2 * j, k2 = 2 * j + 1;
            float m1 = mm[k1], s1 = ss[k1], h1 = hh[k1];
            float m2 = mm[k2], s2 = ss[k2], h2 = hh[k2];
            float i2s1 = 1.0f / (2.0f * s1 * s1);
            float i2s2 = 1.0f / (2.0f * s2 * s2);
            const float scale = 1.0f / ((float)NF * (float)NF);
            int xcol = x0 + rr_;
#pragma unroll
            for (int p2 = 0; p2 < 8; ++p2) {
                int y = 64 * p2 + bb_;
                float u1 = x[p2].x * scale, u2 = x[p2].y * scale;
                float d1 = u1 - m1, d2 = u2 - m2;
                size_t o = (size_t)xcol * NF + y;
                G[(size_t)k1 * NF2 + o] = (2.0f * expf(-d1 * d1 * i2s1) - 1.0f) * h1;
                G[(size_t)k2 * NF2 + o] = (2.0f * expf(-d2 * d2 * i2s2) - 1.0f) * h2;
            }
        }
        __syncthreads();
    }
    grid.sync();

    // ---------- Phase 4: combine + flow + reintegration (halo recompute). ----------
    {
        float* sUp0 = (float*)&RS[0][0];           // 3*HT2 + HT2 + 3*HT2 = 40,432 B <= RS
        float* sUp1 = sUp0 + HT2;
        float* sUp2 = sUp1 + HT2;
        float* sAs  = sUp2 + HT2;
        float* sA0  = sAs + HT2;
        float* sA1  = sA0 + HT2;
        float* sA2  = sA1 + HT2;
        float* sM   = (float*)&SCA[0][0];          // 6*CT2 = 31,104 B <= SCA
        int X0 = (blk >> 4) * 32, Y0 = (blk & 15) * 32;

        float w0[10], w1[10], w2[10];
#pragma unroll
        for (int k = 0; k < 10; ++k) {
            w0[k] = (float)c1[k * 3 + 0];
            w1[k] = (float)c1[k * 3 + 1];
            w2[k] = (float)c1[k * 3 + 2];
        }

        for (int i = tid; i < HT2; i += 512) {
            int lx = i / HT, ly = i - lx * HT;
            int xg = (X0 - 3 + lx) & (NF - 1);
            int yg = (Y0 - 3 + ly) & (NF - 1);
            int gid = xg * NF + yg;
            float a0 = 0.f, a1 = 0.f, a2 = 0.f;
#pragma unroll
            for (int k = 0; k < 10; ++k) {
                float g = G[(size_t)k * NF2 + gid];
                a0 += g * w0[k]; a1 += g * w1[k]; a2 += g * w2[k];
            }
            sUp0[i] = a0; sUp1[i] = a1; sUp2[i] = a2;
            float A0 = A[gid * 3 + 0], A1 = A[gid * 3 + 1], A2 = A[gid * 3 + 2];
            sA0[i] = A0; sA1[i] = A1; sA2[i] = A2;
            sAs[i] = A0 + A1 + A2;
        }
        __syncthreads();

        for (int i = tid; i < CT2; i += 512) {
            int lx = i / CT, ly = i - lx * CT;
            int ci = (lx + 1) * HT + (ly + 1);
            int xg = (X0 - 2 + lx) & (NF - 1);
            int yg = (Y0 - 2 + ly) & (NF - 1);

            auto grad38 = [&](const float* f, float& gx, float& gy) {
                float fmm = f[ci - HT - 1], fm0 = f[ci - HT], fmp = f[ci - HT + 1];
                float f0m = f[ci - 1], f0p = f[ci + 1];
                float fpm = f[ci + HT - 1], fp0 = f[ci + HT], fpp = f[ci + HT + 1];
                gx = (fpm + 2.0f * fp0 + fpp - fmm - 2.0f * fm0 - fmp) * 0.125f;
                gy = (fmp + 2.0f * f0p + fpp - fmm - 2.0f * f0m - fpm) * 0.125f;
            };
            float gax, gay;
            grad38(sAs, gax, gay);
            float px = (float)xg + 0.5f, py = (float)yg + 0.5f;
            const float* sUpc[3] = {sUp0, sUp1, sUp2};
            const float* sAc[3] = {sA0, sA1, sA2};
#pragma unroll
            for (int c = 0; c < 3; ++c) {
                float gux, guy;
                grad38(sUpc[c], gux, guy);
                float a = sAc[c][ci];
                float al = fminf(a * a, 1.0f);
                float Fx = gux * (1.0f - al) - gax * al;
                float Fy = guy * (1.0f - al) - gay * al;
                Fx = fminf(fmaxf(Fx, -4.35f), 4.35f);   // ma = DD - SIGMA
                Fy = fminf(fmaxf(Fy, -4.35f), 4.35f);
                sM[c * CT2 + i] = px + 0.2f * Fx;        // DT = 0.2
                sM[(3 + c) * CT2 + i] = py + 0.2f * Fy;
            }
        }
        __syncthreads();

        const float INV_NORM = (float)(1.0 / (4.0 * 0.65 * 0.65));
        int cy = tid & 31, cx0 = tid >> 5;              // cx0 in [0,16)
        const float* sAc[3] = {sA0, sA1, sA2};
        for (int sidx = 0; sidx < 2; ++sidx) {
            int cx = cx0 + 16 * sidx;
            int x = X0 + cx, y = Y0 + cy;
            float px = (float)x + 0.5f, py = (float)y + 0.5f;
            float acc0 = 0.f, acc1 = 0.f, acc2 = 0.f;
#pragma unroll
            for (int dx = 0; dx < 5; ++dx)
#pragma unroll
                for (int dy = 0; dy < 5; ++dy) {
                    int li36 = (cx + dx) * CT + (cy + dy);
                    int li38 = (cx + dx + 1) * HT + (cy + dy + 1);
#pragma unroll
                    for (int c = 0; c < 3; ++c) {
                        float mux = sM[c * CT2 + li36], muy = sM[(3 + c) * CT2 + li36];
                        float szx = 0.5f - fabsf(px - mux) + 0.65f;
                        float szy = 0.5f - fabsf(py - muy) + 0.65f;
                        szx = fminf(fmaxf(szx, 0.0f), 1.0f);
                        szy = fminf(fmaxf(szy, 0.0f), 1.0f);
                        float area = szx * szy * INV_NORM;
                        float v = sAc[c][li38] * area;
                        if (c == 0) acc0 += v;
                        else if (c == 1) acc1 += v;
                        else acc2 += v;
                    }
                }
            int gid = x * NF + y;
            out[gid * 3 + 0] = acc0;
            out[gid * 3 + 1] = acc1;
            out[gid * 3 + 2] = acc2;
        }
    }
}

extern "C" void kernel_launch(void* const* d_in, const int* in_sizes, int n_in,
                              void* d_out, int out_size, void* d_ws, size_t ws_size,
                              hipStream_t stream) {
    (void)in_sizes; (void)n_in; (void)out_size; (void)ws_size;
    const float* A  = (const float*)d_in[0];
    const float* nK = (const float*)d_in[1];
    const float* m  = (const float*)d_in[2];
    const float* s  = (const float*)d_in[3];
    const float* h  = (const float*)d_in[4];
    const int*   c0 = (const int*)d_in[5];
    const int*   c1 = (const int*)d_in[6];
    float* out = (float*)d_out;

    char* ws = (char*)d_ws;
    // Z: 7 packed complex planes = 14,680,064 B @ 0; tmpT: 5 planes @ 14,680,064.
    // G (10 real planes, 10.5 MB) aliases Z (dead after phase 2). Total 25.2 MB.
    float2* Z    = (float2*)ws;
    float2* tmpT = (float2*)(ws + 14680064);
    float*  G    = (float*)ws;

    void* args[] = {(void*)&A, (void*)&nK, (void*)&m, (void*)&s, (void*)&h,
                    (void*)&c0, (void*)&c1, (void*)&Z, (void*)&tmpT, (void*)&G,
                    (void*)&out};
    hipLaunchCooperativeKernel((const void*)k_mega, dim3(256), dim3(512), args, 0, stream);
}